// Round 2
// baseline (8646.499 us; speedup 1.0000x reference)
//
#include <hip/hip_runtime.h>
#include <hip/hip_bf16.h>
#include <hip/hip_fp16.h>

#define B_ 64
#define T_ 1024
#define I_ 256
#define H_ 512
#define O_ 256

// packed 4 fp16 weights (4 consecutive k for one column j)
struct __align__(8) h2x2 { __half2 a, b; };

// ---------------------------------------------------------------- K0: pack W_hh -> fp16, layout [q][j], q = k/4
__global__ __launch_bounds__(256) void k_pack_whh(const float* __restrict__ whh, h2x2* __restrict__ out) {
    int idx = blockIdx.x * 256 + threadIdx.x;    // 0 .. 128*512-1
    int q = idx >> 9;                            // 0..127
    int j = idx & 511;
    int k = q * 4;
    h2x2 r;
    r.a = __floats2half2_rn(whh[(size_t)k * H_ + j],       whh[(size_t)(k + 1) * H_ + j]);
    r.b = __floats2half2_rn(whh[(size_t)(k + 2) * H_ + j], whh[(size_t)(k + 3) * H_ + j]);
    out[idx] = r;
}

// ---------------------------------------------------------------- K1: xW = x @ W_xh + b_h   [65536,256]@[256,512]
__global__ __launch_bounds__(256) void k_xw(const float* __restrict__ A,
                                            const float* __restrict__ Bw,
                                            const float* __restrict__ bias,
                                            float* __restrict__ C) {
    __shared__ float As[16][64 + 4];   // [k][m], row stride 68 floats (272B, 16B-aligned)
    __shared__ float Bs[16][64 + 4];   // [k][n]
    const int tid = threadIdx.x;
    const int tx = tid & 15, ty = tid >> 4;
    const int bm = blockIdx.y * 64;
    const int bn = blockIdx.x * 64;
    float acc[4][4] = {};

    for (int k0 = 0; k0 < I_; k0 += 16) {
        {   // A tile: 64 rows x 16 k, float4 along k
            int r = tid >> 2, kq = (tid & 3) * 4;
            float4 v = *reinterpret_cast<const float4*>(&A[(size_t)(bm + r) * I_ + k0 + kq]);
            As[kq + 0][r] = v.x; As[kq + 1][r] = v.y; As[kq + 2][r] = v.z; As[kq + 3][r] = v.w;
        }
        {   // B tile: 16 k x 64 n
            int kr = tid >> 4, nq = (tid & 15) * 4;
            float4 v = *reinterpret_cast<const float4*>(&Bw[(size_t)(k0 + kr) * H_ + bn + nq]);
            *reinterpret_cast<float4*>(&Bs[kr][nq]) = v;
        }
        __syncthreads();
        #pragma unroll
        for (int kk = 0; kk < 16; ++kk) {
            float a[4], b[4];
            *reinterpret_cast<float4*>(a) = *reinterpret_cast<const float4*>(&As[kk][ty * 4]);
            *reinterpret_cast<float4*>(b) = *reinterpret_cast<const float4*>(&Bs[kk][tx * 4]);
            #pragma unroll
            for (int i = 0; i < 4; ++i)
                #pragma unroll
                for (int jx = 0; jx < 4; ++jx)
                    acc[i][jx] = fmaf(a[i], b[jx], acc[i][jx]);
        }
        __syncthreads();
    }
    #pragma unroll
    for (int i = 0; i < 4; ++i) {
        int r = bm + ty * 4 + i;
        float4 o;
        o.x = acc[i][0] + bias[bn + tx * 4 + 0];
        o.y = acc[i][1] + bias[bn + tx * 4 + 1];
        o.z = acc[i][2] + bias[bn + tx * 4 + 2];
        o.w = acc[i][3] + bias[bn + tx * 4 + 3];
        *reinterpret_cast<float4*>(&C[(size_t)r * H_ + bn + tx * 4]) = o;
    }
}

// ---------------------------------------------------------------- K2: persistent recurrence, 1 block per batch row
// h = tanh(xw_t + h @ W_hh); h_t overwrites xw slot; h kept fp32 in LDS; W_hh fp16 streamed from L2.
__global__ __launch_bounds__(1024) void k_rnn(const h2x2* __restrict__ Wq,   // [128][512]
                                              float* __restrict__ HA,        // [B,T,H] in: xw, out: h
                                              const float* __restrict__ h0,
                                              float* __restrict__ hT) {
    __shared__ __align__(16) float h_lds[H_];
    __shared__ float part[H_];
    const int b = blockIdx.x;
    const int tid = threadIdx.x;
    const int j = tid & 511;
    const int hf = tid >> 9;                 // k-half: 0 or 1

    if (tid < H_) h_lds[tid] = h0[(size_t)b * H_ + tid];
    __syncthreads();

    float* harow = HA + (size_t)b * T_ * H_;
    const h2x2* wp = Wq + (size_t)(hf * 64) * H_ + j;          // this thread's column slice
    const float4* h4 = reinterpret_cast<const float4*>(h_lds) + hf * 64;

    for (int t = 0; t < T_; ++t) {
        float acc0 = 0.f, acc1 = 0.f;
        #pragma unroll 8
        for (int q = 0; q < 64; ++q) {
            h2x2 w = wp[(size_t)q * H_];      // 8B coalesced, L2-resident stream
            float4 hv = h4[q];                // LDS broadcast
            float2 w0 = __half22float2(w.a);
            float2 w1 = __half22float2(w.b);
            acc0 = fmaf(w0.x, hv.x, acc0);
            acc1 = fmaf(w0.y, hv.y, acc1);
            acc0 = fmaf(w1.x, hv.z, acc0);
            acc1 = fmaf(w1.y, hv.w, acc1);
        }
        float acc = acc0 + acc1;
        if (hf) part[j] = acc;
        __syncthreads();                      // partials ready; all h reads done
        if (!hf) {
            float pre = harow[(size_t)t * H_ + j] + acc + part[j];
            float hn = tanhf(pre);
            harow[(size_t)t * H_ + j] = hn;   // store h_t for the output GEMM
            h_lds[j] = hn;                    // update recurrent state
        }
        __syncthreads();                      // h_{t} visible to both halves
    }
    if (tid < H_) hT[(size_t)b * H_ + tid] = h_lds[tid];
}

// ---------------------------------------------------------------- K3: y = softmax(H @ W_hy + b_y)  fused
__global__ __launch_bounds__(256) void k_out(const float* __restrict__ Hh,   // [M,512]
                                             const float* __restrict__ Wy,   // [512,256]
                                             const float* __restrict__ by,   // [256]
                                             float* __restrict__ out) {      // [M,256]
    __shared__ float Hs[16][64 + 4];     // [k][m]
    __shared__ float Ws[16][256];        // [k][n]
    const int tid = threadIdx.x;
    const int tx = tid & 31, ty = tid >> 5;     // tx: col group (8 cols), ty: row group (8 rows)
    const int m0 = blockIdx.x * 64;
    float acc[8][8] = {};

    for (int k0 = 0; k0 < H_; k0 += 16) {
        {   // H tile
            int r = tid >> 2, kq = (tid & 3) * 4;
            float4 v = *reinterpret_cast<const float4*>(&Hh[(size_t)(m0 + r) * H_ + k0 + kq]);
            Hs[kq + 0][r] = v.x; Hs[kq + 1][r] = v.y; Hs[kq + 2][r] = v.z; Hs[kq + 3][r] = v.w;
        }
        {   // W tile: 16 x 256
            int kr = tid >> 4, c0 = (tid & 15) * 16;
            const float4* src = reinterpret_cast<const float4*>(&Wy[(size_t)(k0 + kr) * O_ + c0]);
            float4* dst = reinterpret_cast<float4*>(&Ws[kr][c0]);
            dst[0] = src[0]; dst[1] = src[1]; dst[2] = src[2]; dst[3] = src[3];
        }
        __syncthreads();
        #pragma unroll
        for (int kk = 0; kk < 16; ++kk) {
            float a[8], bb[8];
            *reinterpret_cast<float4*>(&a[0])  = *reinterpret_cast<const float4*>(&Hs[kk][ty * 8]);
            *reinterpret_cast<float4*>(&a[4])  = *reinterpret_cast<const float4*>(&Hs[kk][ty * 8 + 4]);
            *reinterpret_cast<float4*>(&bb[0]) = *reinterpret_cast<const float4*>(&Ws[kk][tx * 8]);
            *reinterpret_cast<float4*>(&bb[4]) = *reinterpret_cast<const float4*>(&Ws[kk][tx * 8 + 4]);
            #pragma unroll
            for (int i = 0; i < 8; ++i)
                #pragma unroll
                for (int jx = 0; jx < 8; ++jx)
                    acc[i][jx] = fmaf(a[i], bb[jx], acc[i][jx]);
        }
        __syncthreads();
    }

    float bv[8];
    *reinterpret_cast<float4*>(&bv[0]) = *reinterpret_cast<const float4*>(&by[tx * 8]);
    *reinterpret_cast<float4*>(&bv[4]) = *reinterpret_cast<const float4*>(&by[tx * 8 + 4]);

    #pragma unroll
    for (int i = 0; i < 8; ++i) {
        float l[8];
        float mx = -1e30f;
        #pragma unroll
        for (int jx = 0; jx < 8; ++jx) { l[jx] = acc[i][jx] + bv[jx]; mx = fmaxf(mx, l[jx]); }
        // reduce max over the 32 tx-lanes (within a 32-lane half of the wave)
        mx = fmaxf(mx, __shfl_xor(mx, 16));
        mx = fmaxf(mx, __shfl_xor(mx, 8));
        mx = fmaxf(mx, __shfl_xor(mx, 4));
        mx = fmaxf(mx, __shfl_xor(mx, 2));
        mx = fmaxf(mx, __shfl_xor(mx, 1));
        float s = 0.f;
        #pragma unroll
        for (int jx = 0; jx < 8; ++jx) { float e = __expf(l[jx] - mx); l[jx] = e; s += e; }
        s += __shfl_xor(s, 16);
        s += __shfl_xor(s, 8);
        s += __shfl_xor(s, 4);
        s += __shfl_xor(s, 2);
        s += __shfl_xor(s, 1);
        float inv = 1.0f / s;
        #pragma unroll
        for (int jx = 0; jx < 8; ++jx) l[jx] *= inv;
        int m = m0 + ty * 8 + i;
        *reinterpret_cast<float4*>(&out[(size_t)m * O_ + tx * 8])     = *reinterpret_cast<float4*>(&l[0]);
        *reinterpret_cast<float4*>(&out[(size_t)m * O_ + tx * 8 + 4]) = *reinterpret_cast<float4*>(&l[4]);
    }
}

// ----------------------------------------------------------------
extern "C" void kernel_launch(void* const* d_in, const int* in_sizes, int n_in,
                              void* d_out, int out_size, void* d_ws, size_t ws_size,
                              hipStream_t stream) {
    const float* x   = (const float*)d_in[0];   // [B,T,I]
    const float* h0  = (const float*)d_in[1];   // [B,H]
    const float* Wxh = (const float*)d_in[2];   // [I,H]
    const float* Whh = (const float*)d_in[3];   // [H,H]
    const float* bh  = (const float*)d_in[4];   // [H]
    const float* Why = (const float*)d_in[5];   // [H,O]
    const float* byv = (const float*)d_in[6];   // [O]
    float* out = (float*)d_out;

    const size_t HA_BYTES = (size_t)B_ * T_ * H_ * sizeof(float);      // 128 MB
    const size_t WP_BYTES = (size_t)128 * H_ * sizeof(h2x2);           // 512 KB
    if (ws_size < HA_BYTES + WP_BYTES) return;   // fail loudly via wrong output

    float* HA  = (float*)d_ws;
    h2x2* Wq   = (h2x2*)((char*)d_ws + HA_BYTES);

    // pack W_hh to fp16 (runs every call; cheap)
    k_pack_whh<<<256, 256, 0, stream>>>(Whh, Wq);

    // xW = x @ W_xh + b_h  -> HA
    k_xw<<<dim3(H_ / 64, (B_ * T_) / 64), 256, 0, stream>>>(x, Wxh, bh, HA);

    // recurrence: 64 persistent blocks, h_t overwrites HA, h_T -> tail of d_out
    float* hT = out + (size_t)B_ * T_ * O_;
    k_rnn<<<B_, 1024, 0, stream>>>(Wq, HA, h0, hT);

    // outputs = softmax(HA @ W_hy + b_y)
    k_out<<<(B_ * T_) / 64, 256, 0, stream>>>(HA, Why, byv, out);
}

// Round 3
// 4644.145 us; speedup vs baseline: 1.8618x; 1.8618x over previous
//
#include <hip/hip_runtime.h>
#include <hip/hip_bf16.h>
#include <hip/hip_fp16.h>

#define B_ 64
#define T_ 1024
#define I_ 256
#define H_ 512
#define O_ 256

typedef _Float16 h2v __attribute__((ext_vector_type(2)));
union U16x4 { uint4 u; h2v h[4]; _Float16 f[8]; };

// ---------------------------------------------------------------- K0: pack W_hh -> fp16 chunks
// chunk c = q*512 + j holds W[8q+0..8q+7][j] as 8 halfs (16B). q = k/8.
__global__ __launch_bounds__(256) void k_pack_whh(const float* __restrict__ whh, uint4* __restrict__ out) {
    int c = blockIdx.x * 256 + threadIdx.x;      // 0 .. 64*512-1
    int q = c >> 9;
    int j = c & 511;
    U16x4 r;
    #pragma unroll
    for (int i = 0; i < 8; ++i)
        r.f[i] = (_Float16)whh[(size_t)(q * 8 + i) * H_ + j];
    out[c] = r.u;
}

// ---------------------------------------------------------------- K1: xW = x @ W_xh + b_h   [65536,256]@[256,512]
__global__ __launch_bounds__(256) void k_xw(const float* __restrict__ A,
                                            const float* __restrict__ Bw,
                                            const float* __restrict__ bias,
                                            float* __restrict__ C) {
    __shared__ float As[16][64 + 4];
    __shared__ float Bs[16][64 + 4];
    const int tid = threadIdx.x;
    const int tx = tid & 15, ty = tid >> 4;
    const int bm = blockIdx.y * 64;
    const int bn = blockIdx.x * 64;
    float acc[4][4] = {};

    for (int k0 = 0; k0 < I_; k0 += 16) {
        {
            int r = tid >> 2, kq = (tid & 3) * 4;
            float4 v = *reinterpret_cast<const float4*>(&A[(size_t)(bm + r) * I_ + k0 + kq]);
            As[kq + 0][r] = v.x; As[kq + 1][r] = v.y; As[kq + 2][r] = v.z; As[kq + 3][r] = v.w;
        }
        {
            int kr = tid >> 4, nq = (tid & 15) * 4;
            float4 v = *reinterpret_cast<const float4*>(&Bw[(size_t)(k0 + kr) * H_ + bn + nq]);
            *reinterpret_cast<float4*>(&Bs[kr][nq]) = v;
        }
        __syncthreads();
        #pragma unroll
        for (int kk = 0; kk < 16; ++kk) {
            float a[4], b[4];
            *reinterpret_cast<float4*>(a) = *reinterpret_cast<const float4*>(&As[kk][ty * 4]);
            *reinterpret_cast<float4*>(b) = *reinterpret_cast<const float4*>(&Bs[kk][tx * 4]);
            #pragma unroll
            for (int i = 0; i < 4; ++i)
                #pragma unroll
                for (int jx = 0; jx < 4; ++jx)
                    acc[i][jx] = fmaf(a[i], b[jx], acc[i][jx]);
        }
        __syncthreads();
    }
    #pragma unroll
    for (int i = 0; i < 4; ++i) {
        int r = bm + ty * 4 + i;
        float4 o;
        o.x = acc[i][0] + bias[bn + tx * 4 + 0];
        o.y = acc[i][1] + bias[bn + tx * 4 + 1];
        o.z = acc[i][2] + bias[bn + tx * 4 + 2];
        o.w = acc[i][3] + bias[bn + tx * 4 + 3];
        *reinterpret_cast<float4*>(&C[(size_t)r * H_ + bn + tx * 4]) = o;
    }
}

// ---------------------------------------------------------------- K2: persistent recurrence, 1 block per batch row
// 512 threads, thread j owns column j (full k). h in LDS as packed fp16 (double-buffered,
// 1 barrier/step). Inner product via v_dot2_f32_f16 (fp32 accum). W fp16 streamed from L2.
__global__ __launch_bounds__(512) void k_rnn(const uint4* __restrict__ Wp,   // [64][512] 16B chunks
                                             float* __restrict__ HA,         // [B,T,H] in: xw, out: h
                                             const float* __restrict__ h0,
                                             float* __restrict__ hT) {
    __shared__ __align__(16) _Float16 hbuf[2][H_];   // 2 KB
    const int b = blockIdx.x;
    const int j = threadIdx.x;                       // 0..511

    hbuf[0][j] = (_Float16)h0[(size_t)b * H_ + j];
    __syncthreads();

    float* harow = HA + (size_t)b * T_ * H_;
    const uint4* wp = Wp + j;                        // chunk (q=0, col j); stride 512 per q
    float hn = 0.f;
    int cur = 0;

    for (int t = 0; t < T_; ++t) {
        float xw = harow[(size_t)t * H_ + j];        // independent: issue early
        const uint4* hb4 = reinterpret_cast<const uint4*>(&hbuf[cur][0]);
        float acc[4] = {0.f, 0.f, 0.f, 0.f};
        #pragma unroll 4
        for (int q = 0; q < 64; q += 4) {
            #pragma unroll
            for (int u = 0; u < 4; ++u) {
                U16x4 w, h;
                w.u = wp[(size_t)(q + u) << 9];      // 16B coalesced, L2-resident stream
                h.u = hb4[q + u];                    // 8 h-halfs, wave-uniform broadcast
                acc[u] = __builtin_amdgcn_fdot2(w.h[0], h.h[0], acc[u], false);
                acc[u] = __builtin_amdgcn_fdot2(w.h[1], h.h[1], acc[u], false);
                acc[u] = __builtin_amdgcn_fdot2(w.h[2], h.h[2], acc[u], false);
                acc[u] = __builtin_amdgcn_fdot2(w.h[3], h.h[3], acc[u], false);
            }
        }
        float pre = xw + (acc[0] + acc[1]) + (acc[2] + acc[3]);
        hn = tanhf(pre);
        harow[(size_t)t * H_ + j] = hn;              // h_t for the output GEMM (fp32)
        hbuf[cur ^ 1][j] = (_Float16)hn;             // write NEXT buffer: no WAR on cur
        __syncthreads();                             // single barrier per step
        cur ^= 1;
    }
    hT[(size_t)b * H_ + j] = hn;
}

// ---------------------------------------------------------------- K3: y = softmax(H @ W_hy + b_y)  fused
__global__ __launch_bounds__(256) void k_out(const float* __restrict__ Hh,   // [M,512]
                                             const float* __restrict__ Wy,   // [512,256]
                                             const float* __restrict__ by,   // [256]
                                             float* __restrict__ out) {      // [M,256]
    __shared__ float Hs[16][64 + 4];
    __shared__ float Ws[16][256];
    const int tid = threadIdx.x;
    const int tx = tid & 31, ty = tid >> 5;
    const int m0 = blockIdx.x * 64;
    float acc[8][8] = {};

    for (int k0 = 0; k0 < H_; k0 += 16) {
        {
            int r = tid >> 2, kq = (tid & 3) * 4;
            float4 v = *reinterpret_cast<const float4*>(&Hh[(size_t)(m0 + r) * H_ + k0 + kq]);
            Hs[kq + 0][r] = v.x; Hs[kq + 1][r] = v.y; Hs[kq + 2][r] = v.z; Hs[kq + 3][r] = v.w;
        }
        {
            int kr = tid >> 4, c0 = (tid & 15) * 16;
            const float4* src = reinterpret_cast<const float4*>(&Wy[(size_t)(k0 + kr) * O_ + c0]);
            float4* dst = reinterpret_cast<float4*>(&Ws[kr][c0]);
            dst[0] = src[0]; dst[1] = src[1]; dst[2] = src[2]; dst[3] = src[3];
        }
        __syncthreads();
        #pragma unroll
        for (int kk = 0; kk < 16; ++kk) {
            float a[8], bb[8];
            *reinterpret_cast<float4*>(&a[0])  = *reinterpret_cast<const float4*>(&Hs[kk][ty * 8]);
            *reinterpret_cast<float4*>(&a[4])  = *reinterpret_cast<const float4*>(&Hs[kk][ty * 8 + 4]);
            *reinterpret_cast<float4*>(&bb[0]) = *reinterpret_cast<const float4*>(&Ws[kk][tx * 8]);
            *reinterpret_cast<float4*>(&bb[4]) = *reinterpret_cast<const float4*>(&Ws[kk][tx * 8 + 4]);
            #pragma unroll
            for (int i = 0; i < 8; ++i)
                #pragma unroll
                for (int jx = 0; jx < 8; ++jx)
                    acc[i][jx] = fmaf(a[i], bb[jx], acc[i][jx]);
        }
        __syncthreads();
    }

    float bv[8];
    *reinterpret_cast<float4*>(&bv[0]) = *reinterpret_cast<const float4*>(&by[tx * 8]);
    *reinterpret_cast<float4*>(&bv[4]) = *reinterpret_cast<const float4*>(&by[tx * 8 + 4]);

    #pragma unroll
    for (int i = 0; i < 8; ++i) {
        float l[8];
        float mx = -1e30f;
        #pragma unroll
        for (int jx = 0; jx < 8; ++jx) { l[jx] = acc[i][jx] + bv[jx]; mx = fmaxf(mx, l[jx]); }
        mx = fmaxf(mx, __shfl_xor(mx, 16));
        mx = fmaxf(mx, __shfl_xor(mx, 8));
        mx = fmaxf(mx, __shfl_xor(mx, 4));
        mx = fmaxf(mx, __shfl_xor(mx, 2));
        mx = fmaxf(mx, __shfl_xor(mx, 1));
        float s = 0.f;
        #pragma unroll
        for (int jx = 0; jx < 8; ++jx) { float e = __expf(l[jx] - mx); l[jx] = e; s += e; }
        s += __shfl_xor(s, 16);
        s += __shfl_xor(s, 8);
        s += __shfl_xor(s, 4);
        s += __shfl_xor(s, 2);
        s += __shfl_xor(s, 1);
        float inv = 1.0f / s;
        #pragma unroll
        for (int jx = 0; jx < 8; ++jx) l[jx] *= inv;
        int m = m0 + ty * 8 + i;
        *reinterpret_cast<float4*>(&out[(size_t)m * O_ + tx * 8])     = *reinterpret_cast<float4*>(&l[0]);
        *reinterpret_cast<float4*>(&out[(size_t)m * O_ + tx * 8 + 4]) = *reinterpret_cast<float4*>(&l[4]);
    }
}

// ----------------------------------------------------------------
extern "C" void kernel_launch(void* const* d_in, const int* in_sizes, int n_in,
                              void* d_out, int out_size, void* d_ws, size_t ws_size,
                              hipStream_t stream) {
    const float* x   = (const float*)d_in[0];   // [B,T,I]
    const float* h0  = (const float*)d_in[1];   // [B,H]
    const float* Wxh = (const float*)d_in[2];   // [I,H]
    const float* Whh = (const float*)d_in[3];   // [H,H]
    const float* bh  = (const float*)d_in[4];   // [H]
    const float* Why = (const float*)d_in[5];   // [H,O]
    const float* byv = (const float*)d_in[6];   // [O]
    float* out = (float*)d_out;

    const size_t HA_BYTES = (size_t)B_ * T_ * H_ * sizeof(float);      // 128 MB
    const size_t WP_BYTES = (size_t)64 * H_ * sizeof(uint4);           // 512 KB
    if (ws_size < HA_BYTES + WP_BYTES) return;

    float* HA = (float*)d_ws;
    uint4* Wp = (uint4*)((char*)d_ws + HA_BYTES);

    // pack W_hh to fp16 chunks (runs every call; cheap)
    k_pack_whh<<<128, 256, 0, stream>>>(Whh, Wp);

    // xW = x @ W_xh + b_h  -> HA
    k_xw<<<dim3(H_ / 64, (B_ * T_) / 64), 256, 0, stream>>>(x, Wxh, bh, HA);

    // recurrence: 64 persistent blocks, h_t overwrites HA, h_T -> tail of d_out
    float* hT = out + (size_t)B_ * T_ * O_;
    k_rnn<<<B_, 512, 0, stream>>>(Wp, HA, h0, hT);

    // outputs = softmax(HA @ W_hy + b_y)
    k_out<<<(B_ * T_) / 64, 256, 0, stream>>>(HA, Why, byv, out);
}